// Round 1
// baseline (105.517 us; speedup 1.0000x reference)
//
#include <hip/hip_runtime.h>

#define T 4096
#define D 66
#define NL 3

// ---------------------------------------------------------------------------
// Kernel A: 5 MLP jobs, thread-per-row, h in registers, W via uniform loads.
// job 0: Q = MLP(x1, wq, bq), stored row-major (C reads rows per-wave).
// job 1..4: K_m = MLP(x_m, wk, bk), stored TRANSPOSED KT[m][d][t] so the scan
//           kernel loads coalesce. Also writes V2T (first 2 feature cols,
//           transposed) and TM (timestamp column) while the x-row is in regs.
// ---------------------------------------------------------------------------
__global__ __launch_bounds__(64) void mlp_kernel(
    const float* __restrict__ x1, const float* __restrict__ x2,
    const float* __restrict__ x3, const float* __restrict__ x4,
    const float* __restrict__ wq, const float* __restrict__ bq,
    const float* __restrict__ wk, const float* __restrict__ bk,
    float* __restrict__ Q, float* __restrict__ KT,
    float* __restrict__ V2T, float* __restrict__ TM)
{
    const int job = blockIdx.y;            // 0: Q; 1..4: K_{job-1}
    const int r = blockIdx.x * 64 + threadIdx.x;
    const float* X = (job <= 1) ? x1 : (job == 2 ? x2 : (job == 3 ? x3 : x4));
    const float* W = (job == 0) ? wq : wk;
    const float* Bs = (job == 0) ? bq : bk;

    float h[D];
#pragma unroll
    for (int d = 0; d < D; ++d) h[d] = X[r * D + d];

    if (job >= 1) {
        const int m = job - 1;
        V2T[(m * 2 + 0) * T + r] = h[0];
        V2T[(m * 2 + 1) * T + r] = h[1];
        TM[m * T + r]            = h[D - 1];
    }

#pragma unroll 1
    for (int l = 0; l < NL; ++l) {
        const float* Wl = W + l * D * D;   // uniform -> scalar loads
        const float* Bl = Bs + l * D;
        float nh[D];
#pragma unroll
        for (int o = 0; o < D; ++o) nh[o] = Bl[o];
#pragma unroll
        for (int d = 0; d < D; ++d) {
            const float hd = h[d];
#pragma unroll
            for (int o = 0; o < D; ++o) nh[o] = fmaf(hd, Wl[d * D + o], nh[o]);
        }
        const bool relu = (l < NL - 1);
#pragma unroll
        for (int o = 0; o < D; ++o) h[o] = relu ? fmaxf(nh[o], 0.0f) : nh[o];
    }

    if (job == 0) {
#pragma unroll
        for (int d = 0; d < D; ++d) Q[r * D + d] = h[d];
    } else {
        const int m = job - 1;
#pragma unroll
        for (int d = 0; d < D; ++d) KT[(m * D + d) * T + r] = h[d];
    }
}

// ---------------------------------------------------------------------------
// Kernel B: cumulative sum per (m, col) column, col = d*2+v, 528 columns.
// One wave per column. Phase 0: coalesced load of the whole 4096-elem column
// into LDS with XOR swizzle f(j)=j^((j>>6)&31) (conflict-free for both
// j=c*64+lane writes and j=lane*64+c reads). Phase 1: per-lane segment sums.
// Phase 2: 6-step exclusive shuffle scan. Phase 3: per-lane serial scan +
// store to row-major state S[m][j][col] (scattered stores, L2-buffered).
// ---------------------------------------------------------------------------
__global__ __launch_bounds__(128) void scan_kernel(
    const float* __restrict__ KT, const float* __restrict__ V2T,
    float* __restrict__ S)
{
    __shared__ float lds[2][T];
    const int w    = threadIdx.x >> 6;
    const int lane = threadIdx.x & 63;
    const int wgid = blockIdx.x * 2 + w;   // 0..527
    const int col  = wgid >> 2;            // 0..131
    const int m    = wgid & 3;
    const int d    = col >> 1;
    const int v    = col & 1;

    const float* kp = KT + (size_t)(m * D + d) * T;
    const float* vp = V2T + (size_t)(m * 2 + v) * T;
    float* sp = S + (size_t)m * T * 132 + col;

    for (int c = 0; c < 64; ++c) {
        const int j = c * 64 + lane;
        lds[w][j ^ ((j >> 6) & 31)] = kp[j] * vp[j];
    }
    __syncthreads();

    float sum = 0.0f;
    const int j0 = lane * 64;
    for (int c = 0; c < 64; ++c) {
        const int j = j0 + c;
        sum += lds[w][j ^ ((j >> 6) & 31)];
    }

    float inc = sum;
#pragma unroll
    for (int off = 1; off < 64; off <<= 1) {
        float y = __shfl_up(inc, off);
        if (lane >= off) inc += y;
    }
    float run = inc - sum;   // exclusive prefix of this lane's segment

    for (int c = 0; c < 64; ++c) {
        const int j = j0 + c;
        run += lds[w][j ^ ((j >> 6) & 31)];
        sp[(size_t)j * 132] = run;
    }
}

// ---------------------------------------------------------------------------
// Kernel C: one wave per output row i. Lane l holds Q[i][l] (+ Q[i][64+l] for
// lanes 0,1). Per modality: guarded 13-step power-of-two binary search for
// count of t2 <= t1[i] (uniform -> scalar), then lane-parallel dot with the
// 132-float state row (coalesced float2 loads). Shuffle-reduce, lane 0 writes.
// ---------------------------------------------------------------------------
__global__ __launch_bounds__(256) void out_kernel(
    const float* __restrict__ Q, const float* __restrict__ S,
    const float* __restrict__ TM, float* __restrict__ out)
{
    const int w    = threadIdx.x >> 6;
    const int lane = threadIdx.x & 63;
    const int i    = blockIdx.x * 4 + w;

    const float t1i = TM[i];               // modality 0 times == t1
    const float q0  = Q[i * D + lane];
    const float q1  = (lane < 2) ? Q[i * D + 64 + lane] : 0.0f;
    float acc0 = 0.0f, acc1 = 0.0f;

#pragma unroll
    for (int m = 0; m < 4; ++m) {
        const float* t2 = TM + m * T;
        int pos = 0;
#pragma unroll
        for (int step = T; step >= 1; step >>= 1) {
            if (pos + step <= T && t2[pos + step - 1] <= t1i) pos += step;
        }
        const int idx = pos - 1;           // last j with t2[j] <= t1i
        if (idx >= 0) {
            const float* sp = S + ((size_t)m * T + idx) * 132;
            const float2 s0 = *(const float2*)(sp + lane * 2);
            acc0 = fmaf(q0, s0.x, acc0);
            acc1 = fmaf(q0, s0.y, acc1);
            if (lane < 2) {
                const float2 s1 = *(const float2*)(sp + 128 + lane * 2);
                acc0 = fmaf(q1, s1.x, acc0);
                acc1 = fmaf(q1, s1.y, acc1);
            }
        }
    }

#pragma unroll
    for (int off = 32; off >= 1; off >>= 1) {
        acc0 += __shfl_down(acc0, off);
        acc1 += __shfl_down(acc1, off);
    }
    if (lane == 0) {
        out[i * 2 + 0] = acc0;
        out[i * 2 + 1] = acc1;
    }
}

extern "C" void kernel_launch(void* const* d_in, const int* in_sizes, int n_in,
                              void* d_out, int out_size, void* d_ws, size_t ws_size,
                              hipStream_t stream)
{
    (void)in_sizes; (void)n_in; (void)out_size; (void)ws_size;
    const float* x1 = (const float*)d_in[0];
    const float* x2 = (const float*)d_in[1];
    const float* x3 = (const float*)d_in[2];
    const float* x4 = (const float*)d_in[3];
    const float* wq = (const float*)d_in[4];
    const float* bq = (const float*)d_in[5];
    const float* wk = (const float*)d_in[6];
    const float* bk = (const float*)d_in[7];

    float* ws  = (float*)d_ws;
    float* Q   = ws;                 // 4096*66          = 270336
    float* KT  = ws + 270336;        // 4*66*4096        = 1081344
    float* V2T = ws + 1351680;       // 4*2*4096         = 32768
    float* TM  = ws + 1384448;       // 4*4096           = 16384
    float* S   = ws + 1400832;       // 4*4096*132       = 2162688  (end 3563520 floats ~ 14.3 MB)

    mlp_kernel<<<dim3(64, 5), 64, 0, stream>>>(x1, x2, x3, x4, wq, bq, wk, bk,
                                               Q, KT, V2T, TM);
    scan_kernel<<<264, 128, 0, stream>>>(KT, V2T, S);
    out_kernel<<<1024, 256, 0, stream>>>(Q, S, TM, (float*)d_out);
}

// Round 2
// 94.267 us; speedup vs baseline: 1.1193x; 1.1193x over previous
//
#include <hip/hip_runtime.h>

#define T 4096
#define D 66
#define NL 3
#define NC 32          // scan chunks per modality
#define JC 128         // T / NC

// ---------------------------------------------------------------------------
// Kernel A: 5 MLP jobs (job 0: Q from x1/wq; 1..4: K_m from x_m/wk).
// Block = 512 threads (8 waves) handles a 64-row tile. Activations in a
// double-buffered LDS tile hb[2][66*65] ([col][row], row-dim padded to 65 so
// both the transposed load phase and the row-broadcast reads are conflict-
// free). Wave w computes outputs [9w, 9w+9) (last wave 3 real outputs; W
// index clamped so the dead FMAs read in-bounds). Weights go through the
// scalar path (uniform index -> s_load). Outputs stored row-major via LDS
// (coalesced global stores). Only ~20 VGPRs of accumulator -> no spills.
// ---------------------------------------------------------------------------
__global__ __launch_bounds__(512) void mlp_kernel(
    const float* __restrict__ x1, const float* __restrict__ x2,
    const float* __restrict__ x3, const float* __restrict__ x4,
    const float* __restrict__ wq, const float* __restrict__ bq,
    const float* __restrict__ wk, const float* __restrict__ bk,
    float* __restrict__ Q, float* __restrict__ K)
{
    __shared__ float hb[2][66 * 65];
    const int job  = blockIdx.y;           // 0: Q; 1..4: K_{job-1}
    const int tile = blockIdx.x;           // 0..63 (64 rows each)
    const float* X = (job <= 1) ? x1 : (job == 2 ? x2 : (job == 3 ? x3 : x4));
    const float* W = (job == 0) ? wq : wk;
    const float* Bs = (job == 0) ? bq : bk;
    const int t = threadIdx.x;

    // transposed load: x row-major -> hb[0][col*65 + row]
    const float* xt = X + (size_t)tile * 64 * D;
    for (int k = t; k < 64 * D; k += 512) {
        const int row = k / D;
        const int col = k - row * D;
        hb[0][col * 65 + row] = xt[k];
    }
    __syncthreads();

    const int wv   = t >> 6;
    const int lane = t & 63;
    const int o0   = wv * 9;                      // 0,9,...,63
    const int no   = (o0 + 9 <= D) ? 9 : (D - o0); // last wave: 3

    int src = 0;
    float acc[9];
#pragma unroll 1
    for (int l = 0; l < NL; ++l) {
        const float* Wl = W + l * D * D;
        const float* Bl = Bs + l * D;
#pragma unroll
        for (int oi = 0; oi < 9; ++oi) {
            const int o = (o0 + oi < D) ? (o0 + oi) : (D - 1);
            acc[oi] = Bl[o];
        }
        for (int d = 0; d < D; ++d) {
            const float hd = hb[src][d * 65 + lane];
#pragma unroll
            for (int oi = 0; oi < 9; ++oi) {
                const int o = (o0 + oi < D) ? (o0 + oi) : (D - 1); // clamped, in-bounds
                acc[oi] = fmaf(hd, Wl[d * D + o], acc[oi]);
            }
        }
        const bool relu = (l < NL - 1);
#pragma unroll
        for (int oi = 0; oi < 9; ++oi) {
            if (oi < no) {
                const float v = acc[oi];
                hb[1 - src][(o0 + oi) * 65 + lane] = relu ? fmaxf(v, 0.0f) : v;
            }
        }
        __syncthreads();
        src = 1 - src;
    }

    // coalesced row-major store via LDS transpose-read
    float* outp = (job == 0) ? Q : (K + (size_t)(job - 1) * T * D);
    float* ot = outp + (size_t)tile * 64 * D;
    for (int k = t; k < 64 * D; k += 512) {
        const int row = k / D;
        const int col = k - row * D;
        ot[k] = hb[src][col * 65 + row];
    }
}

// ---------------------------------------------------------------------------
// Kernel B1: in-chunk cumsum. Grid (NC, 4): block = 192 threads, thread c
// owns state column c = d*2+v (c < 132). Serial over the chunk's JC rows:
// run += K[j][d] * x[j][v]; store S[m][j][c] -- the 132-float row store is
// fully coalesced (528 B contiguous). Chunk total -> chunkSum[m][ch][c].
// ---------------------------------------------------------------------------
__global__ __launch_bounds__(192) void scan_kernel(
    const float* __restrict__ K,
    const float* __restrict__ x1, const float* __restrict__ x2,
    const float* __restrict__ x3, const float* __restrict__ x4,
    float* __restrict__ S, float* __restrict__ chunkSum)
{
    const int c = threadIdx.x;
    if (c >= 132) return;
    const int ch = blockIdx.x;
    const int m  = blockIdx.y;
    const float* Km = K + (size_t)m * T * D;
    const float* Xm = (m == 0) ? x1 : (m == 1 ? x2 : (m == 2 ? x3 : x4));
    const int d = c >> 1;
    const int v = c & 1;

    float run = 0.0f;
    const int j0 = ch * JC;
#pragma unroll 4
    for (int jj = 0; jj < JC; ++jj) {
        const int j = j0 + jj;
        run = fmaf(Km[(size_t)j * D + d], Xm[(size_t)j * D + v], run);
        S[((size_t)m * T + j) * 132 + c] = run;
    }
    chunkSum[((size_t)m * NC + ch) * 132 + c] = run;
}

// ---------------------------------------------------------------------------
// Kernel B2: exclusive scan of chunk sums. Grid (4): thread c scans the NC
// chunk totals of its column serially.
// ---------------------------------------------------------------------------
__global__ __launch_bounds__(192) void chunkscan_kernel(
    const float* __restrict__ chunkSum, float* __restrict__ chunkOff)
{
    const int c = threadIdx.x;
    if (c >= 132) return;
    const int m = blockIdx.x;
    float run = 0.0f;
    for (int ch = 0; ch < NC; ++ch) {
        chunkOff[((size_t)m * NC + ch) * 132 + c] = run;
        run += chunkSum[((size_t)m * NC + ch) * 132 + c];
    }
}

// ---------------------------------------------------------------------------
// Kernel C: one wave per output row i. Uniform 13-step binary search on the
// timestamp column (scalar path), then lane-parallel dot of Q[i] with
// (S row + chunk offset row), both coalesced 528 B reads. Shuffle-reduce.
// ---------------------------------------------------------------------------
__global__ __launch_bounds__(256) void out_kernel(
    const float* __restrict__ Q, const float* __restrict__ S,
    const float* __restrict__ chunkOff,
    const float* __restrict__ x1, const float* __restrict__ x2,
    const float* __restrict__ x3, const float* __restrict__ x4,
    float* __restrict__ out)
{
    const int w    = threadIdx.x >> 6;
    const int lane = threadIdx.x & 63;
    const int i    = blockIdx.x * 4 + w;

    const float t1i = x1[(size_t)i * D + (D - 1)];
    const float q0  = Q[(size_t)i * D + lane];
    const float q1  = (lane < 2) ? Q[(size_t)i * D + 64 + lane] : 0.0f;
    float acc0 = 0.0f, acc1 = 0.0f;

#pragma unroll 1
    for (int m = 0; m < 4; ++m) {
        const float* Xm = (m == 0) ? x1 : (m == 1 ? x2 : (m == 2 ? x3 : x4));
        int pos = 0;
#pragma unroll
        for (int step = T; step >= 1; step >>= 1) {
            if (pos + step <= T && Xm[(size_t)(pos + step - 1) * D + (D - 1)] <= t1i)
                pos += step;
        }
        const int idx = pos - 1;               // last j with t2[j] <= t1i
        if (idx >= 0) {
            const float* sp = S + ((size_t)m * T + idx) * 132;
            const float* op = chunkOff + ((size_t)m * NC + (idx / JC)) * 132;
            const float2 s0 = *(const float2*)(sp + lane * 2);
            const float2 c0 = *(const float2*)(op + lane * 2);
            acc0 = fmaf(q0, s0.x + c0.x, acc0);
            acc1 = fmaf(q0, s0.y + c0.y, acc1);
            if (lane < 2) {
                const float2 s1 = *(const float2*)(sp + 128 + lane * 2);
                const float2 c1 = *(const float2*)(op + 128 + lane * 2);
                acc0 = fmaf(q1, s1.x + c1.x, acc0);
                acc1 = fmaf(q1, s1.y + c1.y, acc1);
            }
        }
    }

#pragma unroll
    for (int off = 32; off >= 1; off >>= 1) {
        acc0 += __shfl_down(acc0, off);
        acc1 += __shfl_down(acc1, off);
    }
    if (lane == 0) {
        out[(size_t)i * 2 + 0] = acc0;
        out[(size_t)i * 2 + 1] = acc1;
    }
}

extern "C" void kernel_launch(void* const* d_in, const int* in_sizes, int n_in,
                              void* d_out, int out_size, void* d_ws, size_t ws_size,
                              hipStream_t stream)
{
    (void)in_sizes; (void)n_in; (void)out_size; (void)ws_size;
    const float* x1 = (const float*)d_in[0];
    const float* x2 = (const float*)d_in[1];
    const float* x3 = (const float*)d_in[2];
    const float* x4 = (const float*)d_in[3];
    const float* wq = (const float*)d_in[4];
    const float* bq = (const float*)d_in[5];
    const float* wk = (const float*)d_in[6];
    const float* bk = (const float*)d_in[7];

    float* ws = (float*)d_ws;
    float* Q        = ws;                  // 4096*66            = 270336
    float* K        = ws + 270336;         // 4*4096*66          = 1081344
    float* S        = ws + 1351680;        // 4*4096*132         = 2162688
    float* chunkSum = ws + 3514368;        // 4*NC*132           = 16896
    float* chunkOff = ws + 3531264;        // 4*NC*132           = 16896
                                           // total 3548160 floats ~ 14.19 MB

    mlp_kernel<<<dim3(64, 5), 512, 0, stream>>>(x1, x2, x3, x4, wq, bq, wk, bk, Q, K);
    scan_kernel<<<dim3(NC, 4), 192, 0, stream>>>(K, x1, x2, x3, x4, S, chunkSum);
    chunkscan_kernel<<<4, 192, 0, stream>>>(chunkSum, chunkOff);
    out_kernel<<<1024, 256, 0, stream>>>(Q, S, chunkOff, x1, x2, x3, x4, (float*)d_out);
}

// Round 3
// 54.243 us; speedup vs baseline: 1.9452x; 1.7379x over previous
//
#include <hip/hip_runtime.h>

#define T 4096
#define D 66
#define NL 3
#define NC 64          // scan chunks per modality
#define JC 64          // T / NC
#define HS 36          // ht row stride (32 rows + pad, multiple of 4 for b128)
#define WS 68          // W LDS col stride (multiple of 4 for b128)

// ---------------------------------------------------------------------------
// Kernel A: 5 MLP jobs (job 0: Q from x1/wq; 1..4: K_m from x_m/wk).
// Block = 128 threads (2 waves), 32 rows. Register-tiled 4x4 outer product:
// lane (rg=lane>>4, og=lane&15) owns rows r0..r0+3 (r0=wv*16+rg*4) and cols
// og*4..og*4+3 (+ cols 64/65 for og<2). Activations transposed in LDS
// ht[buf][d*HS+row] (b128 = 4 rows); weights staged per layer into LDS at
// stride WS (b128 = 4 cols, 64 consecutive floats per wave -> conflict-free).
// Per d: 2x ds_read_b128 + 1x b32 + 20 FMA -> VALU-bound, no scalar loads.
// ---------------------------------------------------------------------------
__global__ __launch_bounds__(128) void mlp_kernel(
    const float* __restrict__ x1, const float* __restrict__ x2,
    const float* __restrict__ x3, const float* __restrict__ x4,
    const float* __restrict__ wq, const float* __restrict__ bq,
    const float* __restrict__ wk, const float* __restrict__ bk,
    float* __restrict__ Q, float* __restrict__ Kp)
{
    __shared__ float ht[2][D * HS];
    __shared__ float Wl[D * WS];
    const int job  = blockIdx.y;           // 0: Q; 1..4: K_{job-1}
    const int tile = blockIdx.x;           // 0..127 (32 rows each)
    const float* X = (job <= 1) ? x1 : (job == 2 ? x2 : (job == 3 ? x3 : x4));
    const float* W = (job == 0) ? wq : wk;
    const float* Bs = (job == 0) ? bq : bk;
    const int t = threadIdx.x;

    // stage x tile transposed: ht[0][d*HS + r]
    const float* xt = X + (size_t)tile * 32 * D;
    for (int k = t; k < 32 * D; k += 128) {
        const int r = k / D;
        const int d = k - r * D;
        ht[0][d * HS + r] = xt[k];
    }

    const int lane = t & 63;
    const int wv   = t >> 6;
    const int og   = lane & 15;
    const int rg   = lane >> 4;
    const int r0   = wv * 16 + rg * 4;     // rows r0..r0+3
    const int c0   = og * 4;               // cols c0..c0+3

    int src = 0;
#pragma unroll 1
    for (int l = 0; l < NL; ++l) {
        // stage layer weights into LDS (stride WS)
        const float* Wg = W + l * D * D;
        for (int k = t; k < D * D; k += 128) {
            const int d = k / D;
            const int o = k - d * D;
            Wl[d * WS + o] = Wg[k];
        }
        __syncthreads();

        float acc[4][4];
        float acce[4];
        {
            const float b0 = Bs[l * D + c0 + 0];
            const float b1 = Bs[l * D + c0 + 1];
            const float b2 = Bs[l * D + c0 + 2];
            const float b3 = Bs[l * D + c0 + 3];
            const float be = Bs[l * D + 64 + (og & 1)];
#pragma unroll
            for (int ri = 0; ri < 4; ++ri) {
                acc[ri][0] = b0; acc[ri][1] = b1;
                acc[ri][2] = b2; acc[ri][3] = b3;
                acce[ri] = be;
            }
        }

        for (int d = 0; d < D; ++d) {
            const float4 h4 = *(const float4*)&ht[src][d * HS + r0];
            const float4 w4 = *(const float4*)&Wl[d * WS + c0];
            const float we  = Wl[d * WS + 64 + (og & 1)];
            const float hv[4] = {h4.x, h4.y, h4.z, h4.w};
#pragma unroll
            for (int ri = 0; ri < 4; ++ri) {
                acc[ri][0] = fmaf(hv[ri], w4.x, acc[ri][0]);
                acc[ri][1] = fmaf(hv[ri], w4.y, acc[ri][1]);
                acc[ri][2] = fmaf(hv[ri], w4.z, acc[ri][2]);
                acc[ri][3] = fmaf(hv[ri], w4.w, acc[ri][3]);
                acce[ri]   = fmaf(hv[ri], we,  acce[ri]);
            }
        }

        if (l < NL - 1) {
            const int nb = 1 - src;
#pragma unroll
            for (int ri = 0; ri < 4; ++ri) {
#pragma unroll
                for (int ci = 0; ci < 4; ++ci)
                    ht[nb][(c0 + ci) * HS + r0 + ri] = fmaxf(acc[ri][ci], 0.0f);
                if (og < 2)
                    ht[nb][(64 + og) * HS + r0 + ri] = fmaxf(acce[ri], 0.0f);
            }
            __syncthreads();
            src = nb;
        } else {
            float* outp = (job == 0) ? Q : (Kp + (size_t)(job - 1) * T * D);
#pragma unroll
            for (int ri = 0; ri < 4; ++ri) {
                const int row = tile * 32 + r0 + ri;
                float* rp = outp + (size_t)row * D + c0;
                *(float2*)rp       = make_float2(acc[ri][0], acc[ri][1]);
                *((float2*)rp + 1) = make_float2(acc[ri][2], acc[ri][3]);
                if (og < 2) outp[(size_t)row * D + 64 + og] = acce[ri];
            }
        }
    }
}

// ---------------------------------------------------------------------------
// Kernel B1: in-chunk cumsum + timestamp extraction. Grid (NC, 4): thread c
// owns state column c = d*2+v (c < 132). Serial over JC rows with coalesced
// 528 B row stores to S. Threads c<64 also copy the timestamp column into the
// compact TM[m][j] table (keeps out_kernel's binary search in a hot 64 KB).
// ---------------------------------------------------------------------------
__global__ __launch_bounds__(192) void scan_kernel(
    const float* __restrict__ Kp,
    const float* __restrict__ x1, const float* __restrict__ x2,
    const float* __restrict__ x3, const float* __restrict__ x4,
    float* __restrict__ S, float* __restrict__ chunkSum,
    float* __restrict__ TM)
{
    const int c  = threadIdx.x;
    const int ch = blockIdx.x;
    const int m  = blockIdx.y;
    const float* Xm = (m == 0) ? x1 : (m == 1 ? x2 : (m == 2 ? x3 : x4));
    const int j0 = ch * JC;

    if (c < JC) TM[m * T + j0 + c] = Xm[(size_t)(j0 + c) * D + (D - 1)];
    if (c >= 132) return;

    const float* Km = Kp + (size_t)m * T * D;
    const int d = c >> 1;
    const int v = c & 1;

    float run = 0.0f;
#pragma unroll 4
    for (int jj = 0; jj < JC; ++jj) {
        const int j = j0 + jj;
        run = fmaf(Km[(size_t)j * D + d], Xm[(size_t)j * D + v], run);
        S[((size_t)m * T + j) * 132 + c] = run;
    }
    chunkSum[((size_t)m * NC + ch) * 132 + c] = run;
}

// ---------------------------------------------------------------------------
// Kernel B2: exclusive scan of chunk sums. Grid (4): thread c scans its
// column's NC chunk totals serially.
// ---------------------------------------------------------------------------
__global__ __launch_bounds__(192) void chunkscan_kernel(
    const float* __restrict__ chunkSum, float* __restrict__ chunkOff)
{
    const int c = threadIdx.x;
    if (c >= 132) return;
    const int m = blockIdx.x;
    float run = 0.0f;
    for (int ch = 0; ch < NC; ++ch) {
        chunkOff[((size_t)m * NC + ch) * 132 + c] = run;
        run += chunkSum[((size_t)m * NC + ch) * 132 + c];
    }
}

// ---------------------------------------------------------------------------
// Kernel C: one wave per output row i. Uniform 13-step binary search on the
// compact TM table (scalar path, shared tree prefix -> hot), then lane-
// parallel dot of Q[i] with (S row + chunk offset row), coalesced 528 B
// reads. Shuffle-reduce, lane 0 writes the 2 outputs.
// ---------------------------------------------------------------------------
__global__ __launch_bounds__(256) void out_kernel(
    const float* __restrict__ Q, const float* __restrict__ S,
    const float* __restrict__ chunkOff, const float* __restrict__ TM,
    float* __restrict__ out)
{
    const int w    = threadIdx.x >> 6;
    const int lane = threadIdx.x & 63;
    const int i    = blockIdx.x * 4 + w;

    const float t1i = TM[i];               // modality 0 times == t1
    const float q0  = Q[(size_t)i * D + lane];
    const float q1  = (lane < 2) ? Q[(size_t)i * D + 64 + lane] : 0.0f;
    float acc0 = 0.0f, acc1 = 0.0f;

#pragma unroll 1
    for (int m = 0; m < 4; ++m) {
        const float* t2 = TM + m * T;
        int pos = 0;
#pragma unroll
        for (int step = T; step >= 1; step >>= 1) {
            if (pos + step <= T && t2[pos + step - 1] <= t1i) pos += step;
        }
        const int idx = pos - 1;               // last j with t2[j] <= t1i
        if (idx >= 0) {
            const float* sp = S + ((size_t)m * T + idx) * 132;
            const float* op = chunkOff + ((size_t)m * NC + (idx / JC)) * 132;
            const float2 s0 = *(const float2*)(sp + lane * 2);
            const float2 c0 = *(const float2*)(op + lane * 2);
            acc0 = fmaf(q0, s0.x + c0.x, acc0);
            acc1 = fmaf(q0, s0.y + c0.y, acc1);
            if (lane < 2) {
                const float2 s1 = *(const float2*)(sp + 128 + lane * 2);
                const float2 c1 = *(const float2*)(op + 128 + lane * 2);
                acc0 = fmaf(q1, s1.x + c1.x, acc0);
                acc1 = fmaf(q1, s1.y + c1.y, acc1);
            }
        }
    }

#pragma unroll
    for (int off = 32; off >= 1; off >>= 1) {
        acc0 += __shfl_down(acc0, off);
        acc1 += __shfl_down(acc1, off);
    }
    if (lane == 0) {
        out[(size_t)i * 2 + 0] = acc0;
        out[(size_t)i * 2 + 1] = acc1;
    }
}

extern "C" void kernel_launch(void* const* d_in, const int* in_sizes, int n_in,
                              void* d_out, int out_size, void* d_ws, size_t ws_size,
                              hipStream_t stream)
{
    (void)in_sizes; (void)n_in; (void)out_size; (void)ws_size;
    const float* x1 = (const float*)d_in[0];
    const float* x2 = (const float*)d_in[1];
    const float* x3 = (const float*)d_in[2];
    const float* x4 = (const float*)d_in[3];
    const float* wq = (const float*)d_in[4];
    const float* bq = (const float*)d_in[5];
    const float* wk = (const float*)d_in[6];
    const float* bk = (const float*)d_in[7];

    float* ws = (float*)d_ws;
    float* Q        = ws;                  // 4096*66            = 270336
    float* Kp       = ws + 270336;         // 4*4096*66          = 1081344
    float* S        = ws + 1351680;        // 4*4096*132         = 2162688
    float* chunkSum = ws + 3514368;        // 4*NC*132           = 33792
    float* chunkOff = ws + 3548160;        // 4*NC*132           = 33792
    float* TM       = ws + 3581952;        // 4*4096             = 16384
                                           // total 3598336 floats ~ 14.39 MB

    mlp_kernel<<<dim3(128, 5), 128, 0, stream>>>(x1, x2, x3, x4, wq, bq, wk, bk, Q, Kp);
    scan_kernel<<<dim3(NC, 4), 192, 0, stream>>>(Kp, x1, x2, x3, x4, S, chunkSum, TM);
    chunkscan_kernel<<<4, 192, 0, stream>>>(chunkSum, chunkOff);
    out_kernel<<<1024, 256, 0, stream>>>(Q, S, chunkOff, TM, (float*)d_out);
}

// Round 4
// 45.559 us; speedup vs baseline: 2.3160x; 1.1906x over previous
//
#include <hip/hip_runtime.h>

#define T 4096
#define D 66
#define NL 3
#define NC 64          // scan chunks per modality
#define JC 64          // T / NC
#define HS 36          // ht row stride (32 rows + pad, multiple of 4 for b128)
#define WS 68          // W LDS col stride (multiple of 4 for b128)

// ---------------------------------------------------------------------------
// Kernel A: 5 MLP jobs (job 0: Q from x1/wq; 1..4: K_m from x_m/wk).
// Block = 128 threads (2 waves), 32 rows. Register-tiled 4x4 outer product:
// lane (rg=lane>>4, og=lane&15) owns rows r0..r0+3 and cols og*4..og*4+3
// (+ cols 64/65 for og<2). Activations transposed in LDS (b128 = 4 rows);
// weights staged per layer into LDS at stride WS. Inner d-loop unrolled 6x
// (66 = 6*11) so ~12 ds_read_b128 are in flight per batch -- ILP covers the
// ~120 cy LDS latency that the ~1.25 waves/SIMD occupancy cannot.
// ---------------------------------------------------------------------------
__global__ __launch_bounds__(128) void mlp_kernel(
    const float* __restrict__ x1, const float* __restrict__ x2,
    const float* __restrict__ x3, const float* __restrict__ x4,
    const float* __restrict__ wq, const float* __restrict__ bq,
    const float* __restrict__ wk, const float* __restrict__ bk,
    float* __restrict__ Q, float* __restrict__ Kp)
{
    __shared__ float ht[2][D * HS];
    __shared__ float Wl[D * WS];
    const int job  = blockIdx.y;           // 0: Q; 1..4: K_{job-1}
    const int tile = blockIdx.x;           // 0..127 (32 rows each)
    const float* X = (job <= 1) ? x1 : (job == 2 ? x2 : (job == 3 ? x3 : x4));
    const float* W = (job == 0) ? wq : wk;
    const float* Bs = (job == 0) ? bq : bk;
    const int t = threadIdx.x;

    // stage x tile transposed: ht[0][d*HS + r]
    const float* xt = X + (size_t)tile * 32 * D;
#pragma unroll 4
    for (int k = t; k < 32 * D; k += 128) {
        const int r = k / D;
        const int d = k - r * D;
        ht[0][d * HS + r] = xt[k];
    }

    const int lane = t & 63;
    const int wv   = t >> 6;
    const int og   = lane & 15;
    const int rg   = lane >> 4;
    const int r0   = wv * 16 + rg * 4;     // rows r0..r0+3
    const int c0   = og * 4;               // cols c0..c0+3

    int src = 0;
#pragma unroll 1
    for (int l = 0; l < NL; ++l) {
        // stage layer weights into LDS (stride WS)
        const float* Wg = W + l * D * D;
#pragma unroll 4
        for (int k = t; k < D * D; k += 128) {
            const int d = k / D;
            const int o = k - d * D;
            Wl[d * WS + o] = Wg[k];
        }
        __syncthreads();

        float acc[4][4];
        float acce[4];
        {
            const float b0 = Bs[l * D + c0 + 0];
            const float b1 = Bs[l * D + c0 + 1];
            const float b2 = Bs[l * D + c0 + 2];
            const float b3 = Bs[l * D + c0 + 3];
            const float be = Bs[l * D + 64 + (og & 1)];
#pragma unroll
            for (int ri = 0; ri < 4; ++ri) {
                acc[ri][0] = b0; acc[ri][1] = b1;
                acc[ri][2] = b2; acc[ri][3] = b3;
                acce[ri] = be;
            }
        }

#pragma unroll 6
        for (int d = 0; d < D; ++d) {
            const float4 h4 = *(const float4*)&ht[src][d * HS + r0];
            const float4 w4 = *(const float4*)&Wl[d * WS + c0];
            const float we  = Wl[d * WS + 64 + (og & 1)];
            const float hv[4] = {h4.x, h4.y, h4.z, h4.w};
#pragma unroll
            for (int ri = 0; ri < 4; ++ri) {
                acc[ri][0] = fmaf(hv[ri], w4.x, acc[ri][0]);
                acc[ri][1] = fmaf(hv[ri], w4.y, acc[ri][1]);
                acc[ri][2] = fmaf(hv[ri], w4.z, acc[ri][2]);
                acc[ri][3] = fmaf(hv[ri], w4.w, acc[ri][3]);
                acce[ri]   = fmaf(hv[ri], we,  acce[ri]);
            }
        }

        if (l < NL - 1) {
            const int nb = 1 - src;
#pragma unroll
            for (int ri = 0; ri < 4; ++ri) {
#pragma unroll
                for (int ci = 0; ci < 4; ++ci)
                    ht[nb][(c0 + ci) * HS + r0 + ri] = fmaxf(acc[ri][ci], 0.0f);
                if (og < 2)
                    ht[nb][(64 + og) * HS + r0 + ri] = fmaxf(acce[ri], 0.0f);
            }
            __syncthreads();
            src = nb;
        } else {
            float* outp = (job == 0) ? Q : (Kp + (size_t)(job - 1) * T * D);
#pragma unroll
            for (int ri = 0; ri < 4; ++ri) {
                const int row = tile * 32 + r0 + ri;
                float* rp = outp + (size_t)row * D + c0;
                *(float2*)rp       = make_float2(acc[ri][0], acc[ri][1]);
                *((float2*)rp + 1) = make_float2(acc[ri][2], acc[ri][3]);
                if (og < 2) outp[(size_t)row * D + 64 + og] = acce[ri];
            }
        }
    }
}

// ---------------------------------------------------------------------------
// Kernel B1: in-chunk cumsum + timestamp extraction. Grid (NC, 4): thread c
// owns state column c = d*2+v (c < 132). Serial over JC rows with coalesced
// 528 B row stores to S. Threads c<64 also copy the timestamp column into the
// compact TM[m][j] table for out_kernel's search.
// ---------------------------------------------------------------------------
__global__ __launch_bounds__(192) void scan_kernel(
    const float* __restrict__ Kp,
    const float* __restrict__ x1, const float* __restrict__ x2,
    const float* __restrict__ x3, const float* __restrict__ x4,
    float* __restrict__ S, float* __restrict__ chunkSum,
    float* __restrict__ TM)
{
    const int c  = threadIdx.x;
    const int ch = blockIdx.x;
    const int m  = blockIdx.y;
    const float* Xm = (m == 0) ? x1 : (m == 1 ? x2 : (m == 2 ? x3 : x4));
    const int j0 = ch * JC;

    if (c < JC) TM[m * T + j0 + c] = Xm[(size_t)(j0 + c) * D + (D - 1)];
    if (c >= 132) return;

    const float* Km = Kp + (size_t)m * T * D;
    const int d = c >> 1;
    const int v = c & 1;

    float run = 0.0f;
#pragma unroll 8
    for (int jj = 0; jj < JC; ++jj) {
        const int j = j0 + jj;
        run = fmaf(Km[(size_t)j * D + d], Xm[(size_t)j * D + v], run);
        S[((size_t)m * T + j) * 132 + c] = run;
    }
    chunkSum[((size_t)m * NC + ch) * 132 + c] = run;
}

// ---------------------------------------------------------------------------
// Kernel B2: exclusive scan of chunk sums. Grid (4): thread c scans its
// column's NC chunk totals serially.
// ---------------------------------------------------------------------------
__global__ __launch_bounds__(192) void chunkscan_kernel(
    const float* __restrict__ chunkSum, float* __restrict__ chunkOff)
{
    const int c = threadIdx.x;
    if (c >= 132) return;
    const int m = blockIdx.x;
    float run = 0.0f;
    for (int ch = 0; ch < NC; ++ch) {
        chunkOff[((size_t)m * NC + ch) * 132 + c] = run;
        run += chunkSum[((size_t)m * NC + ch) * 132 + c];
    }
}

// ---------------------------------------------------------------------------
// Kernel C: one wave per output row i. Wave-cooperative 2-round search:
// round 1 probes the 64 segment-end timestamps (lane l -> t2[l*64+63]),
// ballot+popcount selects the segment; round 2 probes t2[seg*64+l]. Only 2
// dependent loads per modality (vs 13), all 4 modalities interleaved. Then
// lane-parallel dot of Q[i] with (S row + chunk offset row), shuffle-reduce.
// pos = count(t2 <= t1i) == searchsorted(t2, t1i, 'right'); idx = pos-1.
// ---------------------------------------------------------------------------
__global__ __launch_bounds__(256) void out_kernel(
    const float* __restrict__ Q, const float* __restrict__ S,
    const float* __restrict__ chunkOff, const float* __restrict__ TM,
    float* __restrict__ out)
{
    const int w    = threadIdx.x >> 6;
    const int lane = threadIdx.x & 63;
    const int i    = blockIdx.x * 4 + w;

    const float t1i = TM[i];               // modality 0 times == t1
    const float q0  = Q[(size_t)i * D + lane];
    const float q1  = (lane < 2) ? Q[(size_t)i * D + 64 + lane] : 0.0f;
    float acc0 = 0.0f, acc1 = 0.0f;

    // round 1: all 4 modalities' segment probes issued together
    int seg[4];
#pragma unroll
    for (int m = 0; m < 4; ++m) {
        const float se = TM[m * T + lane * 64 + 63];
        const unsigned long long b = __ballot(se <= t1i);
        const int hi = __popcll(b);        // full segments <= t1i
        seg[m] = (hi < 63) ? hi : 63;      // hi==64 folds into seg 63 (all <=)
    }
    // round 2: in-segment probes (coalesced 256 B), then the S-row dots
    int idx[4];
#pragma unroll
    for (int m = 0; m < 4; ++m) {
        const float sv = TM[m * T + seg[m] * 64 + lane];
        const unsigned long long b = __ballot(sv <= t1i);
        idx[m] = seg[m] * 64 + __popcll(b) - 1;   // pos-1; -1 => none
    }

#pragma unroll
    for (int m = 0; m < 4; ++m) {
        if (idx[m] >= 0) {
            const float* sp = S + ((size_t)m * T + idx[m]) * 132;
            const float* op = chunkOff + ((size_t)m * NC + (idx[m] / JC)) * 132;
            const float2 s0 = *(const float2*)(sp + lane * 2);
            const float2 c0 = *(const float2*)(op + lane * 2);
            acc0 = fmaf(q0, s0.x + c0.x, acc0);
            acc1 = fmaf(q0, s0.y + c0.y, acc1);
            if (lane < 2) {
                const float2 s1 = *(const float2*)(sp + 128 + lane * 2);
                const float2 c1 = *(const float2*)(op + 128 + lane * 2);
                acc0 = fmaf(q1, s1.x + c1.x, acc0);
                acc1 = fmaf(q1, s1.y + c1.y, acc1);
            }
        }
    }

#pragma unroll
    for (int off = 32; off >= 1; off >>= 1) {
        acc0 += __shfl_down(acc0, off);
        acc1 += __shfl_down(acc1, off);
    }
    if (lane == 0) {
        out[(size_t)i * 2 + 0] = acc0;
        out[(size_t)i * 2 + 1] = acc1;
    }
}

extern "C" void kernel_launch(void* const* d_in, const int* in_sizes, int n_in,
                              void* d_out, int out_size, void* d_ws, size_t ws_size,
                              hipStream_t stream)
{
    (void)in_sizes; (void)n_in; (void)out_size; (void)ws_size;
    const float* x1 = (const float*)d_in[0];
    const float* x2 = (const float*)d_in[1];
    const float* x3 = (const float*)d_in[2];
    const float* x4 = (const float*)d_in[3];
    const float* wq = (const float*)d_in[4];
    const float* bq = (const float*)d_in[5];
    const float* wk = (const float*)d_in[6];
    const float* bk = (const float*)d_in[7];

    float* ws = (float*)d_ws;
    float* Q        = ws;                  // 4096*66            = 270336
    float* Kp       = ws + 270336;         // 4*4096*66          = 1081344
    float* S        = ws + 1351680;        // 4*4096*132         = 2162688
    float* chunkSum = ws + 3514368;        // 4*NC*132           = 33792
    float* chunkOff = ws + 3548160;        // 4*NC*132           = 33792
    float* TM       = ws + 3581952;        // 4*4096             = 16384
                                           // total 3598336 floats ~ 14.39 MB

    mlp_kernel<<<dim3(128, 5), 128, 0, stream>>>(x1, x2, x3, x4, wq, bq, wk, bk, Q, Kp);
    scan_kernel<<<dim3(NC, 4), 192, 0, stream>>>(Kp, x1, x2, x3, x4, S, chunkSum, TM);
    chunkscan_kernel<<<4, 192, 0, stream>>>(chunkSum, chunkOff);
    out_kernel<<<1024, 256, 0, stream>>>(Q, S, chunkOff, TM, (float*)d_out);
}

// Round 5
// 39.073 us; speedup vs baseline: 2.7005x; 1.1660x over previous
//
#include <hip/hip_runtime.h>

#define T 4096
#define D 66
#define NL 3
#define NC 64          // scan chunks per modality
#define JC 64          // T / NC
#define HS 36          // ht row stride (32 rows + pad, multiple of 4 for b128)
#define WS 68          // W LDS col stride (multiple of 4 for b128)
#define DD (D * D)     // 4356

// ---------------------------------------------------------------------------
// Kernel A: 5 MLP jobs (job 0: Q from x1/wq; 1..4: K_m from x_m/wk).
// Block = 128 threads (2 waves), 32 rows. Register-tiled 4x4 outer product.
// Weights are PREFETCHED into registers (35/thread) one layer ahead, so the
// global->LDS staging latency hides under the previous layer's d-loop; the
// ds_write + barrier at the top of each layer is the only exposed cost.
// Inner d-loop unrolled 6x so ~12 ds_read_b128 are in flight per batch.
// ---------------------------------------------------------------------------
__global__ __launch_bounds__(128) void mlp_kernel(
    const float* __restrict__ x1, const float* __restrict__ x2,
    const float* __restrict__ x3, const float* __restrict__ x4,
    const float* __restrict__ wq, const float* __restrict__ bq,
    const float* __restrict__ wk, const float* __restrict__ bk,
    float* __restrict__ Q, float* __restrict__ Kp)
{
    __shared__ float ht[2][D * HS];
    __shared__ float Wl[D * WS];
    const int job  = blockIdx.y;           // 0: Q; 1..4: K_{job-1}
    const int tile = blockIdx.x;           // 0..127 (32 rows each)
    const float* X = (job <= 1) ? x1 : (job == 2 ? x2 : (job == 3 ? x3 : x4));
    const float* W = (job == 0) ? wq : wk;
    const float* Bs = (job == 0) ? bq : bk;
    const int t = threadIdx.x;

    // stage x tile transposed: ht[0][d*HS + r]
    const float* xt = X + (size_t)tile * 32 * D;
#pragma unroll 4
    for (int k = t; k < 32 * D; k += 128) {
        const int r = k / D;
        const int d = k - r * D;
        ht[0][d * HS + r] = xt[k];
    }

    // prefetch layer-0 weights into registers (in flight with ht staging)
    float wreg[35];
#pragma unroll
    for (int i = 0; i < 35; ++i) {
        const int k = t + i * 128;
        if (k < DD) wreg[i] = W[k];
    }

    const int lane = t & 63;
    const int wv   = t >> 6;
    const int og   = lane & 15;
    const int rg   = lane >> 4;
    const int r0   = wv * 16 + rg * 4;     // rows r0..r0+3
    const int c0   = og * 4;               // cols c0..c0+3

    int src = 0;
#pragma unroll 1
    for (int l = 0; l < NL; ++l) {
        // write prefetched weights into LDS (stride WS)
#pragma unroll
        for (int i = 0; i < 35; ++i) {
            const int k = t + i * 128;
            if (k < DD) {
                const int d = k / D;
                const int o = k - d * D;
                Wl[d * WS + o] = wreg[i];
            }
        }
        __syncthreads();

        // prefetch next layer's weights (latency hides under this d-loop)
        if (l < NL - 1) {
            const float* Wg = W + (l + 1) * DD;
#pragma unroll
            for (int i = 0; i < 35; ++i) {
                const int k = t + i * 128;
                if (k < DD) wreg[i] = Wg[k];
            }
        }

        float acc[4][4];
        float acce[4];
        {
            const float b0 = Bs[l * D + c0 + 0];
            const float b1 = Bs[l * D + c0 + 1];
            const float b2 = Bs[l * D + c0 + 2];
            const float b3 = Bs[l * D + c0 + 3];
            const float be = Bs[l * D + 64 + (og & 1)];
#pragma unroll
            for (int ri = 0; ri < 4; ++ri) {
                acc[ri][0] = b0; acc[ri][1] = b1;
                acc[ri][2] = b2; acc[ri][3] = b3;
                acce[ri] = be;
            }
        }

#pragma unroll 6
        for (int d = 0; d < D; ++d) {
            const float4 h4 = *(const float4*)&ht[src][d * HS + r0];
            const float4 w4 = *(const float4*)&Wl[d * WS + c0];
            const float we  = Wl[d * WS + 64 + (og & 1)];
            const float hv[4] = {h4.x, h4.y, h4.z, h4.w};
#pragma unroll
            for (int ri = 0; ri < 4; ++ri) {
                acc[ri][0] = fmaf(hv[ri], w4.x, acc[ri][0]);
                acc[ri][1] = fmaf(hv[ri], w4.y, acc[ri][1]);
                acc[ri][2] = fmaf(hv[ri], w4.z, acc[ri][2]);
                acc[ri][3] = fmaf(hv[ri], w4.w, acc[ri][3]);
                acce[ri]   = fmaf(hv[ri], we,  acce[ri]);
            }
        }

        if (l < NL - 1) {
            const int nb = 1 - src;
#pragma unroll
            for (int ri = 0; ri < 4; ++ri) {
#pragma unroll
                for (int ci = 0; ci < 4; ++ci)
                    ht[nb][(c0 + ci) * HS + r0 + ri] = fmaxf(acc[ri][ci], 0.0f);
                if (og < 2)
                    ht[nb][(64 + og) * HS + r0 + ri] = fmaxf(acce[ri], 0.0f);
            }
            __syncthreads();   // also protects Wl for next layer's ds_write
            src = nb;
        } else {
            float* outp = (job == 0) ? Q : (Kp + (size_t)(job - 1) * T * D);
#pragma unroll
            for (int ri = 0; ri < 4; ++ri) {
                const int row = tile * 32 + r0 + ri;
                float* rp = outp + (size_t)row * D + c0;
                *(float2*)rp       = make_float2(acc[ri][0], acc[ri][1]);
                *((float2*)rp + 1) = make_float2(acc[ri][2], acc[ri][3]);
                if (og < 2) outp[(size_t)row * D + 64 + og] = acce[ri];
            }
        }
    }
}

// ---------------------------------------------------------------------------
// Kernel B1: in-chunk cumsum + timestamp extraction. Grid (NC, 4): thread c
// owns state column c = d*2+v (c < 132). Serial over JC rows with coalesced
// 528 B row stores to S. Threads c<64 also copy the timestamp column into the
// compact TM[m][j] table for out_kernel's search.
// ---------------------------------------------------------------------------
__global__ __launch_bounds__(192) void scan_kernel(
    const float* __restrict__ Kp,
    const float* __restrict__ x1, const float* __restrict__ x2,
    const float* __restrict__ x3, const float* __restrict__ x4,
    float* __restrict__ S, float* __restrict__ chunkSum,
    float* __restrict__ TM)
{
    const int c  = threadIdx.x;
    const int ch = blockIdx.x;
    const int m  = blockIdx.y;
    const float* Xm = (m == 0) ? x1 : (m == 1 ? x2 : (m == 2 ? x3 : x4));
    const int j0 = ch * JC;

    if (c < JC) TM[m * T + j0 + c] = Xm[(size_t)(j0 + c) * D + (D - 1)];
    if (c >= 132) return;

    const float* Km = Kp + (size_t)m * T * D;
    const int d = c >> 1;
    const int v = c & 1;

    float run = 0.0f;
#pragma unroll 8
    for (int jj = 0; jj < JC; ++jj) {
        const int j = j0 + jj;
        run = fmaf(Km[(size_t)j * D + d], Xm[(size_t)j * D + v], run);
        S[((size_t)m * T + j) * 132 + c] = run;
    }
    chunkSum[((size_t)m * NC + ch) * 132 + c] = run;
}

// ---------------------------------------------------------------------------
// Kernel B2: exclusive scan of chunk sums, wave-parallel. One wave per
// (m, column c): lane ch gathers chunkSum[m][ch][c] (one L2 round trip),
// 6-step shuffle inclusive scan, store exclusive prefix. Grid (33, 4), 132
// waves per modality -- replaces 64 serial dependent L2 round trips.
// ---------------------------------------------------------------------------
__global__ __launch_bounds__(256) void chunkscan_kernel(
    const float* __restrict__ chunkSum, float* __restrict__ chunkOff)
{
    const int wv   = threadIdx.x >> 6;
    const int lane = threadIdx.x & 63;     // = chunk index ch (NC == 64)
    const int c    = blockIdx.x * 4 + wv;  // 0..131
    const int m    = blockIdx.y;
    if (c >= 132) return;

    const float v = chunkSum[((size_t)m * NC + lane) * 132 + c];
    float inc = v;
#pragma unroll
    for (int off = 1; off < 64; off <<= 1) {
        const float y = __shfl_up(inc, off);
        if (lane >= off) inc += y;
    }
    chunkOff[((size_t)m * NC + lane) * 132 + c] = inc - v;
}

// ---------------------------------------------------------------------------
// Kernel C: one wave per output row i (4 rows/block). The 4x64 segment-end
// table is staged once per block into LDS (wave w gathers modality w), so
// round 1 of the 2-round cooperative search is an LDS read + ballot. Round 2
// probes t2[seg*64+lane] (coalesced 256 B). Then lane-parallel dot of Q[i]
// with (S row + chunk offset row), shuffle-reduce, lane 0 writes 2 floats.
// ---------------------------------------------------------------------------
__global__ __launch_bounds__(256) void out_kernel(
    const float* __restrict__ Q, const float* __restrict__ S,
    const float* __restrict__ chunkOff, const float* __restrict__ TM,
    float* __restrict__ out)
{
    __shared__ float segEnd[4][64];
    const int w    = threadIdx.x >> 6;
    const int lane = threadIdx.x & 63;
    const int i    = blockIdx.x * 4 + w;

    segEnd[w][lane] = TM[w * T + lane * 64 + 63];   // wave w stages modality w
    const float t1i = TM[i];               // modality 0 times == t1
    const float q0  = Q[(size_t)i * D + lane];
    const float q1  = (lane < 2) ? Q[(size_t)i * D + 64 + lane] : 0.0f;
    float acc0 = 0.0f, acc1 = 0.0f;
    __syncthreads();

    // round 1 (LDS): pick the 64-row segment per modality
    int seg[4];
#pragma unroll
    for (int m = 0; m < 4; ++m) {
        const unsigned long long b = __ballot(segEnd[m][lane] <= t1i);
        const int hi = __popcll(b);
        seg[m] = (hi < 63) ? hi : 63;
    }
    // round 2 (global, coalesced): in-segment position
    int idx[4];
#pragma unroll
    for (int m = 0; m < 4; ++m) {
        const float sv = TM[m * T + seg[m] * 64 + lane];
        const unsigned long long b = __ballot(sv <= t1i);
        idx[m] = seg[m] * 64 + __popcll(b) - 1;   // pos-1; -1 => none
    }

#pragma unroll
    for (int m = 0; m < 4; ++m) {
        if (idx[m] >= 0) {
            const float* sp = S + ((size_t)m * T + idx[m]) * 132;
            const float* op = chunkOff + ((size_t)m * NC + (idx[m] / JC)) * 132;
            const float2 s0 = *(const float2*)(sp + lane * 2);
            const float2 c0 = *(const float2*)(op + lane * 2);
            acc0 = fmaf(q0, s0.x + c0.x, acc0);
            acc1 = fmaf(q0, s0.y + c0.y, acc1);
            if (lane < 2) {
                const float2 s1 = *(const float2*)(sp + 128 + lane * 2);
                const float2 c1 = *(const float2*)(op + 128 + lane * 2);
                acc0 = fmaf(q1, s1.x + c1.x, acc0);
                acc1 = fmaf(q1, s1.y + c1.y, acc1);
            }
        }
    }

#pragma unroll
    for (int off = 32; off >= 1; off >>= 1) {
        acc0 += __shfl_down(acc0, off);
        acc1 += __shfl_down(acc1, off);
    }
    if (lane == 0) {
        out[(size_t)i * 2 + 0] = acc0;
        out[(size_t)i * 2 + 1] = acc1;
    }
}

extern "C" void kernel_launch(void* const* d_in, const int* in_sizes, int n_in,
                              void* d_out, int out_size, void* d_ws, size_t ws_size,
                              hipStream_t stream)
{
    (void)in_sizes; (void)n_in; (void)out_size; (void)ws_size;
    const float* x1 = (const float*)d_in[0];
    const float* x2 = (const float*)d_in[1];
    const float* x3 = (const float*)d_in[2];
    const float* x4 = (const float*)d_in[3];
    const float* wq = (const float*)d_in[4];
    const float* bq = (const float*)d_in[5];
    const float* wk = (const float*)d_in[6];
    const float* bk = (const float*)d_in[7];

    float* ws = (float*)d_ws;
    float* Q        = ws;                  // 4096*66            = 270336
    float* Kp       = ws + 270336;         // 4*4096*66          = 1081344
    float* S        = ws + 1351680;        // 4*4096*132         = 2162688
    float* chunkSum = ws + 3514368;        // 4*NC*132           = 33792
    float* chunkOff = ws + 3548160;        // 4*NC*132           = 33792
    float* TM       = ws + 3581952;        // 4*4096             = 16384
                                           // total 3598336 floats ~ 14.39 MB

    mlp_kernel<<<dim3(128, 5), 128, 0, stream>>>(x1, x2, x3, x4, wq, bq, wk, bk, Q, Kp);
    scan_kernel<<<dim3(NC, 4), 192, 0, stream>>>(Kp, x1, x2, x3, x4, S, chunkSum, TM);
    chunkscan_kernel<<<dim3(33, 4), 256, 0, stream>>>(chunkSum, chunkOff);
    out_kernel<<<1024, 256, 0, stream>>>(Q, S, chunkOff, TM, (float*)d_out);
}